// Round 1
// baseline (183.261 us; speedup 1.0000x reference)
//
#include <hip/hip_runtime.h>
#include <hip/hip_bf16.h>

#define NB 64
#define S_ 1024
#define D_ 128

typedef __attribute__((ext_vector_type(8))) short bf16x8;
typedef __attribute__((ext_vector_type(4))) float f32x4;

__device__ __forceinline__ unsigned short f2bf(float f) {
  __hip_bfloat16 h = __float2bfloat16(f);
  return __builtin_bit_cast(unsigned short, h);
}

__device__ __forceinline__ void async_copy16(const void* g, void* l) {
  __builtin_amdgcn_global_load_lds(
      (const __attribute__((address_space(1))) unsigned int*)g,
      (__attribute__((address_space(3))) unsigned int*)l, 16, 0, 0);
}

// ---------------- per-batch mean / rstd over S*D = 131072 elements ----------
__global__ __launch_bounds__(256) void stats_kernel(const float* __restrict__ x,
                                                    float2* __restrict__ st) {
  const int b = blockIdx.x, t = threadIdx.x;
  const float4* xb = (const float4*)(x + (size_t)b * S_ * D_);
  float s = 0.f, q = 0.f;
#pragma unroll 4
  for (int i = 0; i < 128; ++i) {
    float4 v = xb[i * 256 + t];
    s += v.x + v.y + v.z + v.w;
    q += v.x * v.x + v.y * v.y + v.z * v.z + v.w * v.w;
  }
  __shared__ float ss[256], sq[256];
  ss[t] = s; sq[t] = q;
  __syncthreads();
  for (int o = 128; o > 0; o >>= 1) {
    if (t < o) { ss[t] += ss[t + o]; sq[t] += sq[t + o]; }
    __syncthreads();
  }
  if (t == 0) {
    const float inv = 1.0f / (S_ * D_);
    float mean = ss[0] * inv;
    float var = sq[0] * inv - mean * mean;
    st[b] = make_float2(mean, rsqrtf(var + 1e-5f));
  }
}

// ---------------- pack W1/W2 -> tril-masked bf16 -----------------------------
__global__ __launch_bounds__(256) void packw_kernel(const float* __restrict__ W1,
                                                    const float* __restrict__ W2,
                                                    unsigned short* __restrict__ W1b,
                                                    unsigned short* __restrict__ W2b) {
  const int id = blockIdx.x * 256 + threadIdx.x;          // 0 .. 524287
  const int perW = (S_ * S_) / 4;                          // 262144 float4 per W
  const float* src = (id < perW) ? W1 : W2;
  unsigned short* dst = (id < perW) ? W1b : W2b;
  const int i4 = (id < perW) ? id : id - perW;
  const int flat = i4 * 4;
  const int trow = flat >> 10;       // row t
  const int scol = flat & 1023;      // col s
  float4 v = ((const float4*)src)[i4];
  ushort4 o;
  o.x = f2bf((scol + 0 <= trow) ? v.x : 0.f);
  o.y = f2bf((scol + 1 <= trow) ? v.y : 0.f);
  o.z = f2bf((scol + 2 <= trow) ? v.z : 0.f);
  o.w = f2bf((scol + 3 <= trow) ? v.w : 0.f);
  *(ushort4*)(dst + flat) = o;
}

// ------------- normalize + transpose: hT[b][d][s] (bf16) ---------------------
__global__ __launch_bounds__(256) void norm_t_kernel(const float* __restrict__ x,
                                                     const float* __restrict__ w,
                                                     const float* __restrict__ bb,
                                                     const float2* __restrict__ st,
                                                     unsigned short* __restrict__ hT) {
  __shared__ unsigned short lds[128 * 72];   // [d][s-tile 64 + 8 pad]
  const int blk = blockIdx.x;
  const int b = blk >> 4;
  const int s0 = (blk & 15) * 64;
  const int t = threadIdx.x;
  const float2 ms = st[b];
  const float4* xb = (const float4*)(x + ((size_t)b * S_ + s0) * D_);
  const float4* wb = (const float4*)(w + (size_t)s0 * D_);
  const float4* bv4 = (const float4*)(bb + (size_t)s0 * D_);
#pragma unroll
  for (int r = 0; r < 8; ++r) {
    const int f = r * 256 + t;
    const int srow = f >> 5;          // 0..63
    const int c4 = f & 31;            // float4 col
    float4 xv = xb[f];
    float4 wv = wb[f];
    float4 bvv = bv4[f];
    const float mu = ms.x, rs = ms.y;
    float h0 = (xv.x - mu) * rs * wv.x + bvv.x;
    float h1 = (xv.y - mu) * rs * wv.y + bvv.y;
    float h2 = (xv.z - mu) * rs * wv.z + bvv.z;
    float h3 = (xv.w - mu) * rs * wv.w + bvv.w;
    const int d0 = c4 * 4;
    lds[(d0 + 0) * 72 + srow] = f2bf(h0);
    lds[(d0 + 1) * 72 + srow] = f2bf(h1);
    lds[(d0 + 2) * 72 + srow] = f2bf(h2);
    lds[(d0 + 3) * 72 + srow] = f2bf(h3);
  }
  __syncthreads();
  unsigned short* outp = hT + (size_t)b * D_ * S_;
#pragma unroll
  for (int rr = 0; rr < 4; ++rr) {
    const int idx = rr * 256 + t;     // 0..1023
    const int d = idx >> 3;           // 0..127
    const int ch = idx & 7;           // 16B chunk within 64-wide s tile
    uint4 v = *(const uint4*)(lds + d * 72 + ch * 8);
    *(uint4*)(outp + d * S_ + s0 + ch * 8) = v;
  }
}

// ------------- causal batched GEMM: C = A(tril SxS) * Bt^T -------------------
// A: (S,S) bf16 masked row-major. Bt: (NB, D, S) bf16 ("B^T": row=n(d), col=k(s)).
// HSWISH=true : Ut[b][d][t] = bf16(hardswish(C))  (for GEMM1)
// HSWISH=false: Out[b][t][d] = Xres[b][t][d] + C  (for GEMM2, fp32)
template <bool HSWISH>
__global__ __launch_bounds__(256, 2) void gemm_causal(
    const unsigned short* __restrict__ Wm, const unsigned short* __restrict__ Bt,
    unsigned short* __restrict__ Ut, const float* __restrict__ Xres,
    float* __restrict__ Out) {
  __shared__ __align__(16) char smem[34816];
  unsigned short* ldsA = (unsigned short*)smem;            // 128 x 32
  unsigned short* ldsB = (unsigned short*)(smem + 8192);   // 128 x 32
  unsigned short* ldsT = (unsigned short*)smem;            // 128 x 136 (epilogue)

  const int t = threadIdx.x;
  const int wave = t >> 6, lane = t & 63;
  const int quad = lane >> 4, l16 = lane & 15;
  const int wm = (wave >> 1) * 64, wn = (wave & 1) * 64;

  const int mt = blockIdx.x & 7;
  const int b = blockIdx.x >> 3;
  const int row0 = mt * 128;

  const unsigned short* gA = Wm + (size_t)row0 * S_;
  const unsigned short* gB = Bt + (size_t)b * D_ * S_;

  // staging slot for this thread: slot r -> row slot>>2, col8 (slot&3)*8
  const int a0row = t >> 2, a0col = (t & 3) * 8;

  f32x4 acc[4][4] = {};

  const int kend = row0 + 128;
  for (int k0 = 0; k0 < kend; k0 += 32) {
    // round 0: slots 0..255 ; round 1: slots 256..511
    async_copy16(gA + a0row * S_ + k0 + a0col, ldsA + t * 8);
    async_copy16(gB + a0row * S_ + k0 + a0col, ldsB + t * 8);
    async_copy16(gA + (a0row + 64) * S_ + k0 + a0col, ldsA + (t + 256) * 8);
    async_copy16(gB + (a0row + 64) * S_ + k0 + a0col, ldsB + (t + 256) * 8);
    __syncthreads();
    bf16x8 af[4], bfr[4];
#pragma unroll
    for (int i = 0; i < 4; ++i)
      af[i] = *(const bf16x8*)(ldsA + (wm + i * 16 + l16) * 32 + quad * 8);
#pragma unroll
    for (int j = 0; j < 4; ++j)
      bfr[j] = *(const bf16x8*)(ldsB + (wn + j * 16 + l16) * 32 + quad * 8);
#pragma unroll
    for (int i = 0; i < 4; ++i)
#pragma unroll
      for (int j = 0; j < 4; ++j)
        acc[i][j] = __builtin_amdgcn_mfma_f32_16x16x32_bf16(af[i], bfr[j],
                                                            acc[i][j], 0, 0, 0);
    __syncthreads();
  }

  if (HSWISH) {
    // hardswish, then transpose through LDS -> Ut[b][d][t] coalesced
#pragma unroll
    for (int i = 0; i < 4; ++i)
#pragma unroll
      for (int j = 0; j < 4; ++j) {
        ushort4 pk;
        float v0 = acc[i][j][0], v1 = acc[i][j][1], v2 = acc[i][j][2], v3 = acc[i][j][3];
        pk.x = f2bf(v0 * fminf(fmaxf(v0 + 3.f, 0.f), 6.f) * (1.f / 6.f));
        pk.y = f2bf(v1 * fminf(fmaxf(v1 + 3.f, 0.f), 6.f) * (1.f / 6.f));
        pk.z = f2bf(v2 * fminf(fmaxf(v2 + 3.f, 0.f), 6.f) * (1.f / 6.f));
        pk.w = f2bf(v3 * fminf(fmaxf(v3 + 3.f, 0.f), 6.f) * (1.f / 6.f));
        const int n = wn + j * 16 + l16;            // d
        const int m0 = wm + i * 16 + quad * 4;      // t within tile
        *(ushort4*)(ldsT + n * 136 + m0) = pk;
      }
    __syncthreads();
    unsigned short* gU = Ut + (size_t)b * D_ * S_;
#pragma unroll
    for (int rr = 0; rr < 8; ++rr) {
      const int idx = rr * 256 + t;   // 0..2047
      const int d = idx >> 4;         // 0..127
      const int ch = idx & 15;        // 16B chunk of 128-wide row
      uint4 v = *(const uint4*)(ldsT + d * 136 + ch * 8);
      *(uint4*)(gU + d * S_ + row0 + ch * 8) = v;
    }
  } else {
    float* gO = Out + (size_t)b * S_ * D_;
    const float* gX = Xres + (size_t)b * S_ * D_;
#pragma unroll
    for (int i = 0; i < 4; ++i) {
      const int mrow0 = row0 + wm + i * 16 + quad * 4;
#pragma unroll
      for (int j = 0; j < 4; ++j) {
        const int col = wn + j * 16 + l16;
#pragma unroll
        for (int r = 0; r < 4; ++r) {
          const int addr = (mrow0 + r) * D_ + col;
          gO[addr] = gX[addr] + acc[i][j][r];
        }
      }
    }
  }
}

extern "C" void kernel_launch(void* const* d_in, const int* in_sizes, int n_in,
                              void* d_out, int out_size, void* d_ws, size_t ws_size,
                              hipStream_t stream) {
  const float* x = (const float*)d_in[0];
  const float* ln_w = (const float*)d_in[1];
  const float* ln_b = (const float*)d_in[2];
  const float* W1 = (const float*)d_in[3];
  const float* W2 = (const float*)d_in[4];
  float* out = (float*)d_out;

  char* ws = (char*)d_ws;
  float2* st = (float2*)ws;                                  // 512 B
  unsigned short* W1b = (unsigned short*)(ws + 4096);        // 2 MiB
  unsigned short* W2b = W1b + (size_t)S_ * S_;               // 2 MiB
  unsigned short* hT = W2b + (size_t)S_ * S_;                // 16 MiB
  unsigned short* uT = hT + (size_t)NB * D_ * S_;            // 16 MiB

  stats_kernel<<<NB, 256, 0, stream>>>(x, st);
  packw_kernel<<<2048, 256, 0, stream>>>(W1, W2, W1b, W2b);
  norm_t_kernel<<<NB * 16, 256, 0, stream>>>(x, ln_w, ln_b, st, hT);
  gemm_causal<true><<<NB * 8, 256, 0, stream>>>(W1b, hT, uT, nullptr, nullptr);
  gemm_causal<false><<<NB * 8, 256, 0, stream>>>(W2b, uT, nullptr, x, out);
}

// Round 2
// 172.439 us; speedup vs baseline: 1.0628x; 1.0628x over previous
//
#include <hip/hip_runtime.h>
#include <hip/hip_bf16.h>

#define NB 64
#define S_ 1024
#define D_ 128

typedef __attribute__((ext_vector_type(8))) short bf16x8;
typedef __attribute__((ext_vector_type(4))) float f32x4;

__device__ __forceinline__ unsigned short f2bf(float f) {
  __hip_bfloat16 h = __float2bfloat16(f);
  return __builtin_bit_cast(unsigned short, h);
}

__device__ __forceinline__ void async_copy16(const void* g, void* l) {
  __builtin_amdgcn_global_load_lds(
      (const __attribute__((address_space(1))) unsigned int*)g,
      (__attribute__((address_space(3))) unsigned int*)l, 16, 0, 0);
}

// ---------------- per-batch mean / rstd over S*D = 131072 elements ----------
__global__ __launch_bounds__(256) void stats_kernel(const float* __restrict__ x,
                                                    float2* __restrict__ st) {
  const int b = blockIdx.x, t = threadIdx.x;
  const float4* xb = (const float4*)(x + (size_t)b * S_ * D_);
  float s = 0.f, q = 0.f;
#pragma unroll 4
  for (int i = 0; i < 128; ++i) {
    float4 v = xb[i * 256 + t];
    s += v.x + v.y + v.z + v.w;
    q += v.x * v.x + v.y * v.y + v.z * v.z + v.w * v.w;
  }
  __shared__ float ss[256], sq[256];
  ss[t] = s; sq[t] = q;
  __syncthreads();
  for (int o = 128; o > 0; o >>= 1) {
    if (t < o) { ss[t] += ss[t + o]; sq[t] += sq[t + o]; }
    __syncthreads();
  }
  if (t == 0) {
    const float inv = 1.0f / (S_ * D_);
    float mean = ss[0] * inv;
    float var = sq[0] * inv - mean * mean;
    st[b] = make_float2(mean, rsqrtf(var + 1e-5f));
  }
}

// ---------------- pack W1/W2 -> tril-masked bf16 -----------------------------
__global__ __launch_bounds__(256) void packw_kernel(const float* __restrict__ W1,
                                                    const float* __restrict__ W2,
                                                    unsigned short* __restrict__ W1b,
                                                    unsigned short* __restrict__ W2b) {
  const int id = blockIdx.x * 256 + threadIdx.x;          // 0 .. 524287
  const int perW = (S_ * S_) / 4;                          // 262144 float4 per W
  const float* src = (id < perW) ? W1 : W2;
  unsigned short* dst = (id < perW) ? W1b : W2b;
  const int i4 = (id < perW) ? id : id - perW;
  const int flat = i4 * 4;
  const int trow = flat >> 10;       // row t
  const int scol = flat & 1023;      // col s
  float4 v = ((const float4*)src)[i4];
  ushort4 o;
  o.x = f2bf((scol + 0 <= trow) ? v.x : 0.f);
  o.y = f2bf((scol + 1 <= trow) ? v.y : 0.f);
  o.z = f2bf((scol + 2 <= trow) ? v.z : 0.f);
  o.w = f2bf((scol + 3 <= trow) ? v.w : 0.f);
  *(ushort4*)(dst + flat) = o;
}

// ------------- normalize + transpose: hT[b][d][s] (bf16) ---------------------
__global__ __launch_bounds__(256) void norm_t_kernel(const float* __restrict__ x,
                                                     const float* __restrict__ w,
                                                     const float* __restrict__ bb,
                                                     const float2* __restrict__ st,
                                                     unsigned short* __restrict__ hT) {
  __shared__ unsigned short lds[128 * 72];   // [d][s-tile 64 + 8 pad]
  const int blk = blockIdx.x;
  const int b = blk >> 4;
  const int s0 = (blk & 15) * 64;
  const int t = threadIdx.x;
  const float2 ms = st[b];
  const float4* xb = (const float4*)(x + ((size_t)b * S_ + s0) * D_);
  const float4* wb = (const float4*)(w + (size_t)s0 * D_);
  const float4* bv4 = (const float4*)(bb + (size_t)s0 * D_);
#pragma unroll
  for (int r = 0; r < 8; ++r) {
    const int f = r * 256 + t;
    const int srow = f >> 5;          // 0..63
    const int c4 = f & 31;            // float4 col
    float4 xv = xb[f];
    float4 wv = wb[f];
    float4 bvv = bv4[f];
    const float mu = ms.x, rs = ms.y;
    float h0 = (xv.x - mu) * rs * wv.x + bvv.x;
    float h1 = (xv.y - mu) * rs * wv.y + bvv.y;
    float h2 = (xv.z - mu) * rs * wv.z + bvv.z;
    float h3 = (xv.w - mu) * rs * wv.w + bvv.w;
    const int d0 = c4 * 4;
    lds[(d0 + 0) * 72 + srow] = f2bf(h0);
    lds[(d0 + 1) * 72 + srow] = f2bf(h1);
    lds[(d0 + 2) * 72 + srow] = f2bf(h2);
    lds[(d0 + 3) * 72 + srow] = f2bf(h3);
  }
  __syncthreads();
  unsigned short* outp = hT + (size_t)b * D_ * S_;
#pragma unroll
  for (int rr = 0; rr < 4; ++rr) {
    const int idx = rr * 256 + t;     // 0..1023
    const int d = idx >> 3;           // 0..127
    const int ch = idx & 7;           // 16B chunk within 64-wide s tile
    uint4 v = *(const uint4*)(lds + d * 72 + ch * 8);
    *(uint4*)(outp + d * S_ + s0 + ch * 8) = v;
  }
}

// ------------- causal batched GEMM: C = A(tril SxS) * Bt^T -------------------
// BM=64 (t), BN=128 (d), BK=32. grid = 1024 blocks, 4 blocks/CU.
// Block index permutation balances causal k-trips across quadrants so that
// round-robin-assigned co-resident blocks {i, i+256, i+512, i+768} have a
// constant summed trip count.
// A: (S,S) bf16 tril-masked row-major. Bt: (NB, D, S) bf16.
// HSWISH=true : Ut[b][d][t] = bf16(hardswish(C))
// HSWISH=false: Out[b][t][d] = Xres[b][t][d] + C  (fp32)
template <bool HSWISH>
__global__ __launch_bounds__(256, 4) void gemm_causal(
    const unsigned short* __restrict__ Wm, const unsigned short* __restrict__ Bt,
    unsigned short* __restrict__ Ut, const float* __restrict__ Xres,
    float* __restrict__ Out) {
  __shared__ __align__(16) char smem[18432];
  unsigned short* ldsA = (unsigned short*)smem;            // 64 x 32
  unsigned short* ldsB = (unsigned short*)(smem + 4096);   // 128 x 32
  unsigned short* ldsT = (unsigned short*)smem;            // 128 x 72 (epilogue)

  const int t = threadIdx.x;
  const int wave = t >> 6, lane = t & 63;
  const int quad = lane >> 4, l16 = lane & 15;
  const int wm = (wave >> 1) * 32, wn = (wave & 1) * 64;

  // balanced (b, mt) decode
  const int bi = blockIdx.x;
  const int q = bi >> 8, r = bi & 255;
  const int b = q * 16 + (r >> 4);
  const int jj = r & 15;
  const int mt = (q & 1) ? (15 - jj) : jj;    // 16 M-tiles of 64 rows
  const int row0 = mt * 64;

  const unsigned short* gA = Wm + (size_t)row0 * S_;
  const unsigned short* gB = Bt + (size_t)b * D_ * S_;

  const int srow = t >> 2, scol = (t & 3) * 8;

  f32x4 acc[2][4] = {};

  const int kend = row0 + 64;
  for (int k0 = 0; k0 < kend; k0 += 32) {
    async_copy16(gA + srow * S_ + k0 + scol, ldsA + t * 8);
    async_copy16(gB + srow * S_ + k0 + scol, ldsB + t * 8);
    async_copy16(gB + (srow + 64) * S_ + k0 + scol, ldsB + (t + 256) * 8);
    __syncthreads();
    bf16x8 af[2], bfr[4];
#pragma unroll
    for (int i = 0; i < 2; ++i)
      af[i] = *(const bf16x8*)(ldsA + (wm + i * 16 + l16) * 32 + quad * 8);
#pragma unroll
    for (int j = 0; j < 4; ++j)
      bfr[j] = *(const bf16x8*)(ldsB + (wn + j * 16 + l16) * 32 + quad * 8);
#pragma unroll
    for (int i = 0; i < 2; ++i)
#pragma unroll
      for (int j = 0; j < 4; ++j)
        acc[i][j] = __builtin_amdgcn_mfma_f32_16x16x32_bf16(af[i], bfr[j],
                                                            acc[i][j], 0, 0, 0);
    __syncthreads();
  }

  if (HSWISH) {
    // hardswish, transpose through LDS -> Ut[b][d][t] coalesced
#pragma unroll
    for (int i = 0; i < 2; ++i)
#pragma unroll
      for (int j = 0; j < 4; ++j) {
        ushort4 pk;
        float v0 = acc[i][j][0], v1 = acc[i][j][1], v2 = acc[i][j][2], v3 = acc[i][j][3];
        pk.x = f2bf(v0 * fminf(fmaxf(v0 + 3.f, 0.f), 6.f) * (1.f / 6.f));
        pk.y = f2bf(v1 * fminf(fmaxf(v1 + 3.f, 0.f), 6.f) * (1.f / 6.f));
        pk.z = f2bf(v2 * fminf(fmaxf(v2 + 3.f, 0.f), 6.f) * (1.f / 6.f));
        pk.w = f2bf(v3 * fminf(fmaxf(v3 + 3.f, 0.f), 6.f) * (1.f / 6.f));
        const int n = wn + j * 16 + l16;            // d
        const int m0 = wm + i * 16 + quad * 4;      // t within 64-tile
        *(ushort4*)(ldsT + n * 72 + m0) = pk;
      }
    __syncthreads();
    unsigned short* gU = Ut + (size_t)b * D_ * S_;
#pragma unroll
    for (int rr = 0; rr < 4; ++rr) {
      const int idx = rr * 256 + t;   // 0..1023
      const int d = idx >> 3;         // 0..127
      const int ch = idx & 7;         // 16B chunk of 64-wide row
      uint4 v = *(const uint4*)(ldsT + d * 72 + ch * 8);
      *(uint4*)(gU + d * S_ + row0 + ch * 8) = v;
    }
  } else {
    float* gO = Out + (size_t)b * S_ * D_;
    const float* gX = Xres + (size_t)b * S_ * D_;
#pragma unroll
    for (int i = 0; i < 2; ++i) {
      const int mrow0 = row0 + wm + i * 16 + quad * 4;
#pragma unroll
      for (int j = 0; j < 4; ++j) {
        const int col = wn + j * 16 + l16;
#pragma unroll
        for (int r = 0; r < 4; ++r) {
          const int addr = (mrow0 + r) * D_ + col;
          gO[addr] = gX[addr] + acc[i][j][r];
        }
      }
    }
  }
}

extern "C" void kernel_launch(void* const* d_in, const int* in_sizes, int n_in,
                              void* d_out, int out_size, void* d_ws, size_t ws_size,
                              hipStream_t stream) {
  const float* x = (const float*)d_in[0];
  const float* ln_w = (const float*)d_in[1];
  const float* ln_b = (const float*)d_in[2];
  const float* W1 = (const float*)d_in[3];
  const float* W2 = (const float*)d_in[4];
  float* out = (float*)d_out;

  char* ws = (char*)d_ws;
  float2* st = (float2*)ws;                                  // 512 B
  unsigned short* W1b = (unsigned short*)(ws + 4096);        // 2 MiB
  unsigned short* W2b = W1b + (size_t)S_ * S_;               // 2 MiB
  unsigned short* hT = W2b + (size_t)S_ * S_;                // 16 MiB
  unsigned short* uT = hT + (size_t)NB * D_ * S_;            // 16 MiB

  stats_kernel<<<NB, 256, 0, stream>>>(x, st);
  packw_kernel<<<2048, 256, 0, stream>>>(W1, W2, W1b, W2b);
  norm_t_kernel<<<NB * 16, 256, 0, stream>>>(x, ln_w, ln_b, st, hT);
  gemm_causal<true><<<1024, 256, 0, stream>>>(W1b, hT, uT, nullptr, nullptr);
  gemm_causal<false><<<1024, 256, 0, stream>>>(W2b, uT, nullptr, x, out);
}

// Round 3
// 139.487 us; speedup vs baseline: 1.3138x; 1.2362x over previous
//
#include <hip/hip_runtime.h>
#include <hip/hip_bf16.h>

#define NB 64
#define S_ 1024
#define D_ 128

typedef __attribute__((ext_vector_type(8))) short bf16x8;
typedef __attribute__((ext_vector_type(4))) float f32x4;

__device__ __forceinline__ unsigned short f2bf(float f) {
  __hip_bfloat16 h = __float2bfloat16(f);
  return __builtin_bit_cast(unsigned short, h);
}

__device__ __forceinline__ void async_copy16(const void* g, void* l) {
  __builtin_amdgcn_global_load_lds(
      (const __attribute__((address_space(1))) unsigned int*)g,
      (__attribute__((address_space(3))) unsigned int*)l, 16, 0, 0);
}

// ---- fused: per-batch partial stats (blocks 0..1023) + W pack (1024..3071) --
__global__ __launch_bounds__(256) void prep_kernel(
    const float* __restrict__ x, const float* __restrict__ W1,
    const float* __restrict__ W2, float2* __restrict__ part,
    unsigned short* __restrict__ W1b, unsigned short* __restrict__ W2b) {
  const int blk = blockIdx.x;
  if (blk < 1024) {
    // partial sum/sumsq over an 8192-float chunk of batch b
    const int b = blk >> 4, c = blk & 15, t = threadIdx.x;
    const float4* xb = (const float4*)(x + (size_t)b * (S_ * D_) + c * 8192);
    float s = 0.f, q = 0.f;
#pragma unroll
    for (int i = 0; i < 8; ++i) {
      float4 v = xb[i * 256 + t];
      s += v.x + v.y + v.z + v.w;
      q += v.x * v.x + v.y * v.y + v.z * v.z + v.w * v.w;
    }
#pragma unroll
    for (int o = 32; o > 0; o >>= 1) {
      s += __shfl_down(s, o, 64);
      q += __shfl_down(q, o, 64);
    }
    __shared__ float2 w4[4];
    const int wave = t >> 6, lane = t & 63;
    if (lane == 0) w4[wave] = make_float2(s, q);
    __syncthreads();
    if (t == 0) {
      float ss = 0.f, qq = 0.f;
#pragma unroll
      for (int i = 0; i < 4; ++i) { ss += w4[i].x; qq += w4[i].y; }
      part[blk] = make_float2(ss, qq);
    }
  } else {
    const int id = (blk - 1024) * 256 + threadIdx.x;  // 0 .. 524287
    const int perW = (S_ * S_) / 4;
    const float* src = (id < perW) ? W1 : W2;
    unsigned short* dst = (id < perW) ? W1b : W2b;
    const int i4 = (id < perW) ? id : id - perW;
    const int flat = i4 * 4;
    const int trow = flat >> 10;
    const int scol = flat & 1023;
    float4 v = ((const float4*)src)[i4];
    ushort4 o;
    o.x = f2bf((scol + 0 <= trow) ? v.x : 0.f);
    o.y = f2bf((scol + 1 <= trow) ? v.y : 0.f);
    o.z = f2bf((scol + 2 <= trow) ? v.z : 0.f);
    o.w = f2bf((scol + 3 <= trow) ? v.w : 0.f);
    *(ushort4*)(dst + flat) = o;
  }
}

// ------------- normalize + transpose: hT[b][d][s] (bf16) ---------------------
__global__ __launch_bounds__(256) void norm_t_kernel(const float* __restrict__ x,
                                                     const float* __restrict__ w,
                                                     const float* __restrict__ bb,
                                                     const float2* __restrict__ part,
                                                     unsigned short* __restrict__ hT) {
  __shared__ unsigned short lds[128 * 72];   // [d][s-tile 64 + 8 pad]
  const int blk = blockIdx.x;
  const int b = blk >> 4;
  const int s0 = (blk & 15) * 64;
  const int t = threadIdx.x;
  // finalize stats from 16 partials (scalar, L2-cached)
  float sum = 0.f, sumq = 0.f;
#pragma unroll
  for (int i = 0; i < 16; ++i) {
    float2 p = part[b * 16 + i];
    sum += p.x; sumq += p.y;
  }
  const float inv = 1.0f / (S_ * D_);
  const float mu = sum * inv;
  const float rs = rsqrtf(sumq * inv - mu * mu + 1e-5f);

  const float4* xb = (const float4*)(x + ((size_t)b * S_ + s0) * D_);
  const float4* wb = (const float4*)(w + (size_t)s0 * D_);
  const float4* bv4 = (const float4*)(bb + (size_t)s0 * D_);
#pragma unroll
  for (int r = 0; r < 8; ++r) {
    const int f = r * 256 + t;
    const int srow = f >> 5;          // 0..63
    const int c4 = f & 31;            // float4 col
    float4 xv = xb[f];
    float4 wv = wb[f];
    float4 bvv = bv4[f];
    float h0 = (xv.x - mu) * rs * wv.x + bvv.x;
    float h1 = (xv.y - mu) * rs * wv.y + bvv.y;
    float h2 = (xv.z - mu) * rs * wv.z + bvv.z;
    float h3 = (xv.w - mu) * rs * wv.w + bvv.w;
    const int d0 = c4 * 4;
    lds[(d0 + 0) * 72 + srow] = f2bf(h0);
    lds[(d0 + 1) * 72 + srow] = f2bf(h1);
    lds[(d0 + 2) * 72 + srow] = f2bf(h2);
    lds[(d0 + 3) * 72 + srow] = f2bf(h3);
  }
  __syncthreads();
  unsigned short* outp = hT + (size_t)b * D_ * S_;
#pragma unroll
  for (int rr = 0; rr < 4; ++rr) {
    const int idx = rr * 256 + t;     // 0..1023
    const int d = idx >> 3;           // 0..127
    const int ch = idx & 7;           // 16B chunk within 64-wide s tile
    uint4 v = *(const uint4*)(lds + d * 72 + ch * 8);
    *(uint4*)(outp + d * S_ + s0 + ch * 8) = v;
  }
}

// ------------- causal batched GEMM: C = A(tril SxS) * Bt^T -------------------
// BM=64 (t), BN=128 (d), BK=64 per barrier via two 32-wide sub-buffers
// (keeps the conflict-free 64B row stride that global_load_lds demands).
// Block decode is XCD-aware: xcd = bi&7; all 16 M-tiles of a batch land on one
// XCD so its hT slice (256KB x 8 batches = 2MB) stays L2-resident.
// Co-resident mts per CU = {m, m+4, m+8, m+12} -> causal trips balanced.
template <bool HSWISH>
__global__ __launch_bounds__(256, 4) void gemm_causal(
    const unsigned short* __restrict__ Wm, const unsigned short* __restrict__ Bt,
    unsigned short* __restrict__ Ut, const float* __restrict__ Xres,
    float* __restrict__ Out) {
  __shared__ __align__(16) char smem[24576];
  unsigned short* ldsA0 = (unsigned short*)smem;             // 64 x 32
  unsigned short* ldsB0 = (unsigned short*)(smem + 4096);    // 128 x 32
  unsigned short* ldsA1 = (unsigned short*)(smem + 12288);   // 64 x 32
  unsigned short* ldsB1 = (unsigned short*)(smem + 16384);   // 128 x 32
  unsigned short* ldsT = (unsigned short*)smem;              // 128 x 72 (epilogue)

  const int t = threadIdx.x;
  const int wave = t >> 6, lane = t & 63;
  const int quad = lane >> 4, l16 = lane & 15;
  const int wm = (wave >> 1) * 32, wn = (wave & 1) * 64;

  const int bi = blockIdx.x;
  const int xcd = bi & 7;
  const int slot = bi >> 3;          // 0..127
  const int b = xcd * 8 + (slot & 7);
  const int mt = slot >> 3;          // 0..15
  const int row0 = mt * 64;

  const unsigned short* gA = Wm + (size_t)row0 * S_;
  const unsigned short* gB = Bt + (size_t)b * D_ * S_;

  const int srow = t >> 2, scol = (t & 3) * 8;

  f32x4 acc[2][4] = {};

  const int kend = row0 + 64;        // multiple of 64
  for (int k0 = 0; k0 < kend; k0 += 64) {
    async_copy16(gA + srow * S_ + k0 + scol, ldsA0 + t * 8);
    async_copy16(gB + srow * S_ + k0 + scol, ldsB0 + t * 8);
    async_copy16(gB + (srow + 64) * S_ + k0 + scol, ldsB0 + (t + 256) * 8);
    async_copy16(gA + srow * S_ + k0 + 32 + scol, ldsA1 + t * 8);
    async_copy16(gB + srow * S_ + k0 + 32 + scol, ldsB1 + t * 8);
    async_copy16(gB + (srow + 64) * S_ + k0 + 32 + scol, ldsB1 + (t + 256) * 8);
    __syncthreads();
    bf16x8 af0[2], bf0[4], af1[2], bf1[4];
#pragma unroll
    for (int i = 0; i < 2; ++i) {
      af0[i] = *(const bf16x8*)(ldsA0 + (wm + i * 16 + l16) * 32 + quad * 8);
      af1[i] = *(const bf16x8*)(ldsA1 + (wm + i * 16 + l16) * 32 + quad * 8);
    }
#pragma unroll
    for (int j = 0; j < 4; ++j) {
      bf0[j] = *(const bf16x8*)(ldsB0 + (wn + j * 16 + l16) * 32 + quad * 8);
      bf1[j] = *(const bf16x8*)(ldsB1 + (wn + j * 16 + l16) * 32 + quad * 8);
    }
#pragma unroll
    for (int i = 0; i < 2; ++i)
#pragma unroll
      for (int j = 0; j < 4; ++j)
        acc[i][j] = __builtin_amdgcn_mfma_f32_16x16x32_bf16(af0[i], bf0[j],
                                                            acc[i][j], 0, 0, 0);
#pragma unroll
    for (int i = 0; i < 2; ++i)
#pragma unroll
      for (int j = 0; j < 4; ++j)
        acc[i][j] = __builtin_amdgcn_mfma_f32_16x16x32_bf16(af1[i], bf1[j],
                                                            acc[i][j], 0, 0, 0);
    __syncthreads();
  }

  if (HSWISH) {
#pragma unroll
    for (int i = 0; i < 2; ++i)
#pragma unroll
      for (int j = 0; j < 4; ++j) {
        ushort4 pk;
        float v0 = acc[i][j][0], v1 = acc[i][j][1], v2 = acc[i][j][2], v3 = acc[i][j][3];
        pk.x = f2bf(v0 * fminf(fmaxf(v0 + 3.f, 0.f), 6.f) * (1.f / 6.f));
        pk.y = f2bf(v1 * fminf(fmaxf(v1 + 3.f, 0.f), 6.f) * (1.f / 6.f));
        pk.z = f2bf(v2 * fminf(fmaxf(v2 + 3.f, 0.f), 6.f) * (1.f / 6.f));
        pk.w = f2bf(v3 * fminf(fmaxf(v3 + 3.f, 0.f), 6.f) * (1.f / 6.f));
        const int n = wn + j * 16 + l16;            // d
        const int m0 = wm + i * 16 + quad * 4;      // t within 64-tile
        *(ushort4*)(ldsT + n * 72 + m0) = pk;
      }
    __syncthreads();
    unsigned short* gU = Ut + (size_t)b * D_ * S_;
#pragma unroll
    for (int rr = 0; rr < 4; ++rr) {
      const int idx = rr * 256 + t;   // 0..1023
      const int d = idx >> 3;         // 0..127
      const int ch = idx & 7;         // 16B chunk of 64-wide row
      uint4 v = *(const uint4*)(ldsT + d * 72 + ch * 8);
      *(uint4*)(gU + d * S_ + row0 + ch * 8) = v;
    }
  } else {
    float* gO = Out + (size_t)b * S_ * D_;
    const float* gX = Xres + (size_t)b * S_ * D_;
#pragma unroll
    for (int i = 0; i < 2; ++i) {
      const int mrow0 = row0 + wm + i * 16 + quad * 4;
#pragma unroll
      for (int j = 0; j < 4; ++j) {
        const int col = wn + j * 16 + l16;
#pragma unroll
        for (int r = 0; r < 4; ++r) {
          const int addr = (mrow0 + r) * D_ + col;
          gO[addr] = gX[addr] + acc[i][j][r];
        }
      }
    }
  }
}

extern "C" void kernel_launch(void* const* d_in, const int* in_sizes, int n_in,
                              void* d_out, int out_size, void* d_ws, size_t ws_size,
                              hipStream_t stream) {
  const float* x = (const float*)d_in[0];
  const float* ln_w = (const float*)d_in[1];
  const float* ln_b = (const float*)d_in[2];
  const float* W1 = (const float*)d_in[3];
  const float* W2 = (const float*)d_in[4];
  float* out = (float*)d_out;

  char* ws = (char*)d_ws;
  float2* part = (float2*)ws;                                // 8 KiB
  unsigned short* W1b = (unsigned short*)(ws + 16384);       // 2 MiB
  unsigned short* W2b = W1b + (size_t)S_ * S_;               // 2 MiB
  unsigned short* hT = W2b + (size_t)S_ * S_;                // 16 MiB
  unsigned short* uT = hT + (size_t)NB * D_ * S_;            // 16 MiB

  prep_kernel<<<3072, 256, 0, stream>>>(x, W1, W2, part, W1b, W2b);
  norm_t_kernel<<<NB * 16, 256, 0, stream>>>(x, ln_w, ln_b, part, hT);
  gemm_causal<true><<<1024, 256, 0, stream>>>(W1b, hT, uT, nullptr, nullptr);
  gemm_causal<false><<<1024, 256, 0, stream>>>(W2b, uT, nullptr, x, out);
}